// Round 15
// baseline (1512.333 us; speedup 1.0000x reference)
//
#include <hip/hip_runtime.h>
#include <hip/hip_bf16.h>
#include <stdint.h>

#define DEV static __device__ __forceinline__

typedef __attribute__((ext_vector_type(4))) float f32x4;
typedef __attribute__((ext_vector_type(8))) short bf16x8;
typedef __attribute__((ext_vector_type(4))) float float4v;

constexpr int NBATCH = 4;
constexpr int SEQ    = 2048;
constexpr int DIM    = 2048;      // D
constexpr int NEXP   = 8;
constexpr int HEXP   = 1024;
constexpr int DSH    = 1024;
constexpr int NTOK   = NBATCH * SEQ;       // 8192
constexpr int JEXP   = NEXP * HEXP;        // 8192
constexpr int JTOT   = JEXP + DSH;         // 9216

DEV short f2bf(float f) {
  __hip_bfloat16 b = __float2bfloat16(f);
  union { __hip_bfloat16 b; short s; } u; u.b = b; return u.s;
}

// async global->LDS, 16B per lane; LDS dest is wave-uniform base + lane*16
DEV void gload16(const void* gp, const void* lp) {
  __builtin_amdgcn_global_load_lds(
      (__attribute__((address_space(1))) void*)(uintptr_t)gp,
      (__attribute__((address_space(3))) void*)(uint32_t)(uintptr_t)lp,
      16, 0, 0);
}

// ---------------- x -> bf16 ----------------
__global__ void conv_x_k(const float* __restrict__ x, short* __restrict__ xb) {
  size_t i = (size_t)blockIdx.x * blockDim.x + threadIdx.x;
  const float4v* s = reinterpret_cast<const float4v*>(x) + i * 2;
  float4v a = s[0], b = s[1];
  bf16x8 o;
  o[0] = f2bf(a.x); o[1] = f2bf(a.y); o[2] = f2bf(a.z); o[3] = f2bf(a.w);
  o[4] = f2bf(b.x); o[5] = f2bf(b.y); o[6] = f2bf(b.z); o[7] = f2bf(b.w);
  *reinterpret_cast<bf16x8*>(xb + i * 8) = o;
}

// ---------------- router: logits, softmax, aux partial sums ----------------
__global__ __launch_bounds__(256) void router_k(
    const float* __restrict__ x, const float* __restrict__ Wr,
    const float* __restrict__ br, float* __restrict__ rw,
    float* __restrict__ auxs) {
  const int wave = threadIdx.x >> 6, lane = threadIdx.x & 63;
  const int t = blockIdx.x * 4 + wave;
  const float* xr = x + (size_t)t * DIM;
  float a[NEXP];
#pragma unroll
  for (int e = 0; e < NEXP; ++e) a[e] = 0.f;
  for (int i = 0; i < DIM / 64; ++i) {
    int k = i * 64 + lane;
    float xv = xr[k];
    const float* w = Wr + (size_t)k * NEXP;
#pragma unroll
    for (int e = 0; e < NEXP; ++e) a[e] = fmaf(xv, w[e], a[e]);
  }
#pragma unroll
  for (int e = 0; e < NEXP; ++e) {
    float v = a[e];
#pragma unroll
    for (int off = 32; off > 0; off >>= 1) v += __shfl_xor(v, off, 64);
    a[e] = v + br[e];
  }
  float mx = a[0];
#pragma unroll
  for (int e = 1; e < NEXP; ++e) mx = fmaxf(mx, a[e]);
  float s = 0.f;
#pragma unroll
  for (int e = 0; e < NEXP; ++e) { a[e] = expf(a[e] - mx); s += a[e]; }
  float inv = 1.f / s;
#pragma unroll
  for (int e = 0; e < NEXP; ++e) a[e] *= inv;
  if (lane == 0) {
#pragma unroll
    for (int e = 0; e < NEXP; ++e) rw[(size_t)t * NEXP + e] = a[e];
  }
  __shared__ float blk[NEXP];
  if (threadIdx.x < NEXP) blk[threadIdx.x] = 0.f;
  __syncthreads();
  if (lane == 0) {
#pragma unroll
    for (int e = 0; e < NEXP; ++e) atomicAdd(&blk[e], a[e]);
  }
  __syncthreads();
  if (threadIdx.x < NEXP) atomicAdd(&auxs[threadIdx.x], blk[threadIdx.x]);
}

__global__ void zero_aux_k(float* auxs) {
  if (threadIdx.x < NEXP) auxs[threadIdx.x] = 0.f;
}

__global__ void fin_aux_k(const float* __restrict__ auxs, float* __restrict__ dst) {
  if (threadIdx.x == 0) {
    float s = 0.f;
    for (int e = 0; e < NEXP; ++e) {
      float u = auxs[e] / (float)NTOK - (1.0f / NEXP);
      s += u * u;
    }
    dst[0] = (s / NEXP) * 0.01f;
  }
}

// ---------- W1cat^T chunk: dst[jloc][k] (ld=DIM), j = jbase+jloc ----------
__global__ __launch_bounds__(256) void conv_w1_k(
    const float* __restrict__ W1, const float* __restrict__ Ws1,
    short* __restrict__ dst, int jbase, int jc) {
  __shared__ float tile[64][65];
  const int j0 = jbase + blockIdx.x * 64;
  const int k0 = blockIdx.y * 64;
  const int tx = threadIdx.x & 63;
  const int ty = threadIdx.x >> 6;
#pragma unroll
  for (int i = 0; i < 16; ++i) {
    int kk = ty * 16 + i;
    int j = j0 + tx, k = k0 + kk;
    float v;
    if (j < JEXP) {
      int e = j >> 10, h = j & 1023;
      v = W1[(size_t)e * DIM * HEXP + (size_t)k * HEXP + h];
    } else {
      v = Ws1[(size_t)k * DSH + (j - JEXP)];
    }
    tile[kk][tx] = v;
  }
  __syncthreads();
#pragma unroll
  for (int i = 0; i < 16; ++i) {
    int jj = ty * 16 + i;
    int jloc = j0 - jbase + jj;
    dst[(size_t)jloc * DIM + k0 + tx] = f2bf(tile[tx][jj]);
  }
}

// ---------- W2cat^T chunk: dst[d][jloc] (ld=jc); shared rows pre-scaled 0.1 ----------
__global__ __launch_bounds__(256) void conv_w2_k(
    const float* __restrict__ W2, const float* __restrict__ Ws2,
    short* __restrict__ dst, int jbase, int jc) {
  __shared__ float tile[64][65];
  const int j0 = jbase + blockIdx.x * 64;
  const int d0 = blockIdx.y * 64;
  const int tx = threadIdx.x & 63;
  const int ty = threadIdx.x >> 6;
#pragma unroll
  for (int i = 0; i < 16; ++i) {
    int jj = ty * 16 + i;
    int j = j0 + jj;
    float v;
    if (j < JEXP) {
      int e = j >> 10, h = j & 1023;
      v = W2[(size_t)e * HEXP * DIM + (size_t)h * DIM + d0 + tx];
    } else {
      v = 0.1f * Ws2[(size_t)(j - JEXP) * DIM + d0 + tx];
    }
    tile[jj][tx] = v;
  }
  __syncthreads();
#pragma unroll
  for (int i = 0; i < 16; ++i) {
    int dd = ty * 16 + i;
    dst[(size_t)(d0 + dd) * jc + (j0 - jbase) + tx] = f2bf(tile[tx][dd]);
  }
}

// ===== m201-faithful GEMM: 256x256, BK=64, 8 waves (2M x 4N) of 128x64,
// 2-dbuf 128 KiB LDS (A 2x32KB @0, B 2x32KB @65536), 512 thr, 1 blk/CU.
// Iteration = 2 K-tiles (T0=2i even->buf0, T1->buf1) = 8 phases. Wave (wr,wc)
// reads A-half wr (one 32-row quarter per phase) and B-half wc>>1 (once, ph1;
// frags persist over the tile's 4 phases). Reads/phase: 12,4,4,4.
// DISTRIBUTED staging, 1 half-tile (2 gloads) per phase, order:
//   ph1:A0(T1) ph2:A1(T1) ph3:B0(T2) ph4:B1(T2) ph5:A0(T2) ph6:A1(T2)
//   ph7:B0(T3) ph8:B1(T3)
// vmcnt(4) ONLY at ph4/ph8 (leaves the 2 newest halves in flight):
//   ph4 drains ...A1(T1) -> tile T1 certified for ph5-8; ph8 drains ...A1(T2)
//   -> T2 certified for next iter. Prologue: A0,A1,B0,B1(0),B0,B1(1); vmcnt(4).
// Tail iter: ph1/ph2 still stage A(T1); ph4 -> vmcnt(0); no later stages/waits.
// WAR: B slots freed at ph1/ph5 end-barrier, staged >=2 phases later; A slots
// freed at ph4/ph8, staged next phase. Swizzle (128-B rows): LDS[row][c] holds
// global chunk c^(row&7); read chunk=(ks*4+(lane>>4))^(lane&7) (ks -> byte^64);
// write src chunk=(lane&7)^((lane>>3)&7). 16-lane groups cover all 8
// bank-quads 2-way (free).
template <int MODE>
__global__ __launch_bounds__(512, 2) void gemm8p(
    const short* __restrict__ A, const short* __restrict__ Bt, int K,
    const float* __restrict__ rw,
    const float* __restrict__ bias_a, const float* __restrict__ bias_b,
    short* __restrict__ hOut, int jbase, int jc,
    float* __restrict__ out, int nx) {
  extern __shared__ short smem[];
  const int tid = threadIdx.x;
  const int w = tid >> 6, lane = tid & 63;
  const int wr = w >> 2, wc = w & 3;

  // bijective XCD swizzle
  const int nwg = nx * (NTOK / 256);
  int orig = blockIdx.x;
  const int q = nwg >> 3, r = nwg & 7;
  const int xcd = orig & 7, off = orig >> 3;
  const int bid = (xcd < r ? xcd * (q + 1) : r * (q + 1) + (xcd - r) * q) + off;
  const int bx = bid % nx, by = bid / nx;
  const int m0 = by * 256, n0 = bx * 256;

  f32x4 acc[8][4] = {};

  // per-lane read offset: row(lane&15)*128 + ((lane>>4)^(lane&7))*16
  const int aoff = ((lane & 15) << 7) | ((((lane >> 4) ^ (lane & 7)) & 7) << 4);

  // compile-time wave bases (buf0; buf1 = +32768)
  const char* A0b = (const char*)smem + wr * 16384 + aoff;
  const char* A1b = A0b + 32768;
  const char* B0b = (const char*)smem + 65536 + (wc >> 1) * 16384 + ((wc & 1) << 13) + aoff;
  const char* B1b = B0b + 32768;

  // staging bases (per-lane global source; dest wave-uniform + lane*16)
  const int sr = lane >> 3;
  const int sc = ((lane & 7) ^ (sr & 7)) << 3;
  const short* gA0 = A + (size_t)(m0 + w * 8 + sr) * K + sc;
  const short* gB0 = Bt + (size_t)(n0 + w * 8 + sr) * K + sc;
  const size_t k64 = (size_t)64 * K;
  const int NT = K >> 6;      // even for all our K
  const int NI = NT >> 1;

#define STG_A(TT, MH) { char* d_ = (char*)smem + ((TT)&1)*32768 + (MH)*16384 + w*1024; \
    const short* g_ = gA0 + (size_t)(TT)*64 + (size_t)(MH)*2*k64;                      \
    gload16(g_, d_); gload16(g_ + k64, d_ + 8192); }
#define STG_B(TT, NH) { char* d_ = (char*)smem + 65536 + ((TT)&1)*32768 + (NH)*16384 + w*1024; \
    const short* g_ = gB0 + (size_t)(TT)*64 + (size_t)(NH)*2*k64;                      \
    gload16(g_, d_); gload16(g_ + k64, d_ + 8192); }

#define RD_A(BASE, Q) {                                                                \
    af[0][0] = *(const bf16x8*)((BASE) + (Q)*4096);                                    \
    af[0][1] = *(const bf16x8*)((uintptr_t)((BASE) + (Q)*4096) ^ 64);                  \
    af[1][0] = *(const bf16x8*)((BASE) + (Q)*4096 + 2048);                             \
    af[1][1] = *(const bf16x8*)((uintptr_t)((BASE) + (Q)*4096 + 2048) ^ 64); }
#define RD_B(BASE) { _Pragma("unroll") for (int ni = 0; ni < 4; ++ni) {                \
    bf[ni][0] = *(const bf16x8*)((BASE) + ni*2048);                                    \
    bf[ni][1] = *(const bf16x8*)((uintptr_t)((BASE) + ni*2048) ^ 64); } }
#define MMQ(Q)                                                                         \
    _Pragma("unroll") for (int mi = 0; mi < 2; ++mi)                                   \
    _Pragma("unroll") for (int ni = 0; ni < 4; ++ni)                                   \
    _Pragma("unroll") for (int ks = 0; ks < 2; ++ks)                                   \
      acc[2*(Q)+mi][ni] = __builtin_amdgcn_mfma_f32_16x16x32_bf16(                     \
          af[mi][ks], bf[ni][ks], acc[2*(Q)+mi][ni], 0, 0, 0);
#define BARR  __builtin_amdgcn_s_barrier()
#define LGKM0 { asm volatile("s_waitcnt lgkmcnt(0)" ::: "memory"); __builtin_amdgcn_sched_barrier(0); }
#define PRIO1 __builtin_amdgcn_s_setprio(1)
#define PRIO0 __builtin_amdgcn_s_setprio(0)
#define VM4   asm volatile("s_waitcnt vmcnt(4)" ::: "memory")
#define VM0   asm volatile("s_waitcnt vmcnt(0)" ::: "memory")
#define PHASE_TAIL(Q) BARR; LGKM0; PRIO1; MMQ(Q); PRIO0; BARR;

  // prologue: A0,A1,B0,B1 of tile0; B0,B1 of tile1; certify tile0
  STG_A(0, 0); STG_A(0, 1); STG_B(0, 0); STG_B(0, 1);
  STG_B(1, 0); STG_B(1, 1);
  VM4;
  BARR;

  bf16x8 af[2][2], bf[4][2];

  for (int i = 0; i < NI; ++i) {
    const int ti = 2 * i;
    const bool more = (i + 1 < NI);
    // ---- ph1: tile ti, quarter 0 (reads all B + A q0) ----
    RD_B(B0b);
    RD_A(A0b, 0);
    STG_A(ti + 1, 0);
    asm volatile("s_waitcnt lgkmcnt(8)" ::: "memory");
    PHASE_TAIL(0)
    // ---- ph2: quarter 1 ----
    RD_A(A0b, 1);
    STG_A(ti + 1, 1);
    PHASE_TAIL(1)
    // ---- ph3: quarter 2 ----
    RD_A(A0b, 2);
    if (more) STG_B(ti + 2, 0);
    PHASE_TAIL(2)
    // ---- ph4: quarter 3; certify tile ti+1 ----
    RD_A(A0b, 3);
    if (more) { STG_B(ti + 2, 1); VM4; } else { VM0; }
    PHASE_TAIL(3)
    // ---- ph5: tile ti+1, quarter 0 ----
    RD_B(B1b);
    RD_A(A1b, 0);
    if (more) STG_A(ti + 2, 0);
    asm volatile("s_waitcnt lgkmcnt(8)" ::: "memory");
    PHASE_TAIL(0)
    // ---- ph6: quarter 1 ----
    RD_A(A1b, 1);
    if (more) STG_A(ti + 2, 1);
    PHASE_TAIL(1)
    // ---- ph7: quarter 2 ----
    RD_A(A1b, 2);
    if (more) STG_B(ti + 3, 0);
    PHASE_TAIL(2)
    // ---- ph8: quarter 3; certify tile ti+2 ----
    RD_A(A1b, 3);
    if (more) { STG_B(ti + 3, 1); VM4; }
    PHASE_TAIL(3)
  }
#undef STG_A
#undef STG_B
#undef RD_A
#undef RD_B
#undef MMQ
#undef VM4
#undef VM0
#undef PHASE_TAIL

  // ---------------- epilogue (16x16 C/D layout, 8x4 acc) ----------------
  const int r0 = (lane >> 4) * 4;
  const int ccol = lane & 15;
#pragma unroll
  for (int m = 0; m < 8; ++m) {
#pragma unroll
    for (int i = 0; i < 4; ++i) {
      const int trow = m0 + wr * 128 + m * 16 + r0 + i;
      if (MODE == 0) {
#pragma unroll
        for (int n = 0; n < 4; ++n) {
          const int col = n0 + wc * 64 + n * 16 + ccol;
          const int j = jbase + col;
          float v = acc[m][n][i];
          float bias = (j < JEXP) ? bias_a[j] : bias_b[j - JEXP];
          float val = v + bias;
          float g = 0.5f * val * (1.0f + erff(val * 0.70710678118654752f));
          float wgt = (j < JEXP) ? rw[(size_t)trow * NEXP + (j >> 10)] : 1.0f;
          hOut[(size_t)trow * jc + col] = f2bf(g * wgt);
        }
      } else if (MODE == 1) {
        float rw8[8];
#pragma unroll
        for (int e = 0; e < 8; ++e) rw8[e] = rw[(size_t)trow * NEXP + e];
#pragma unroll
        for (int n = 0; n < 4; ++n) {
          const int col = n0 + wc * 64 + n * 16 + ccol;
          float bias = 0.1f * bias_b[col];
#pragma unroll
          for (int e = 0; e < 8; ++e) bias += rw8[e] * bias_a[(size_t)e * DIM + col];
          out[(size_t)trow * DIM + col] = acc[m][n][i] + bias;
        }
      } else {
#pragma unroll
        for (int n = 0; n < 4; ++n) {
          const int col = n0 + wc * 64 + n * 16 + ccol;
          out[(size_t)trow * DIM + col] += acc[m][n][i];
        }
      }
    }
  }
}

// ================= fallback 128x128 GEMM (round-1, proven) =================
template <int MODE>
__global__ __launch_bounds__(256) void gemm128(
    const short* __restrict__ A, const short* __restrict__ Bt, int K,
    const float* __restrict__ rw,
    const float* __restrict__ bias_a, const float* __restrict__ bias_b,
    short* __restrict__ hOut, int jbase, int jc,
    float* __restrict__ out) {
  __shared__ short As[128 * 64];
  __shared__ short Bs[128 * 64];
  const int tid = threadIdx.x;
  const int wave = tid >> 6, lane = tid & 63;
  const int wr = wave >> 1, wc = wave & 1;
  const int m0 = blockIdx.y * 128;
  const int n0 = blockIdx.x * 128;

  f32x4 acc[4][4] = {};

  const int srow = wave * 8 + (lane >> 3);
  const int scol = (((lane & 7) ^ (lane >> 3)) << 3);
  const short* gA = A + (size_t)(m0 + srow) * K + scol;
  const short* gB = Bt + (size_t)(n0 + srow) * K + scol;
  const short* lA = As + wave * 512;
  const short* lB = Bs + wave * 512;

  const int rrow = lane & 15;
  const int koff = lane >> 4;
  const int kxor = lane & 7;

  for (int kt = 0; kt < K; kt += 64) {
#pragma unroll
    for (int i = 0; i < 4; ++i) {
      gload16(gA + (size_t)i * 32 * K + kt, lA + i * 2048);
      gload16(gB + (size_t)i * 32 * K + kt, lB + i * 2048);
    }
    asm volatile("s_waitcnt vmcnt(0)" ::: "memory");
    __syncthreads();
#pragma unroll
    for (int kk = 0; kk < 2; ++kk) {
      bf16x8 af[4], bfv[4];
#pragma unroll
      for (int m = 0; m < 4; ++m) {
        int row = wr * 64 + m * 16 + rrow;
        int chunk = (kk * 4 + koff) ^ kxor;
        af[m] = *reinterpret_cast<const bf16x8*>(&As[row * 64 + chunk * 8]);
      }
#pragma unroll
      for (int n = 0; n < 4; ++n) {
        int row = wc * 64 + n * 16 + rrow;
        int chunk = (kk * 4 + koff) ^ kxor;
        bfv[n] = *reinterpret_cast<const bf16x8*>(&Bs[row * 64 + chunk * 8]);
      }
#pragma unroll
      for (int m = 0; m < 4; ++m)
#pragma unroll
        for (int n = 0; n < 4; ++n)
          acc[m][n] = __builtin_amdgcn_mfma_f32_16x16x32_bf16(af[m], bfv[n], acc[m][n], 0, 0, 0);
    }
    __syncthreads();
  }

  const int r0 = (lane >> 4) * 4;
  const int ccol = lane & 15;
#pragma unroll
  for (int m = 0; m < 4; ++m) {
#pragma unroll
    for (int n = 0; n < 4; ++n) {
      int col = n0 + wc * 64 + n * 16 + ccol;
#pragma unroll
      for (int i = 0; i < 4; ++i) {
        int t = m0 + wr * 64 + m * 16 + r0 + i;
        float v = acc[m][n][i];
        if (MODE == 0) {
          int j = jbase + col;
          float bias = (j < JEXP) ? bias_a[j] : bias_b[j - JEXP];
          float val = v + bias;
          float g = 0.5f * val * (1.0f + erff(val * 0.70710678118654752f));
          float wg = (j < JEXP) ? rw[(size_t)t * NEXP + (j >> 10)] : 1.0f;
          hOut[(size_t)t * jc + col] = f2bf(g * wg);
        } else if (MODE == 1) {
          float bias = 0.1f * bias_b[col];
#pragma unroll
          for (int e = 0; e < NEXP; ++e)
            bias += rw[(size_t)t * NEXP + e] * bias_a[(size_t)e * DIM + col];
          out[(size_t)t * DIM + col] = v + bias;
        } else {
          out[(size_t)t * DIM + col] += v;
        }
      }
    }
  }
}

extern "C" void kernel_launch(void* const* d_in, const int* in_sizes, int n_in,
                              void* d_out, int out_size, void* d_ws, size_t ws_size,
                              hipStream_t stream) {
  const float* x   = (const float*)d_in[0];
  const float* Wr  = (const float*)d_in[1];
  const float* br  = (const float*)d_in[2];
  const float* W1  = (const float*)d_in[3];
  const float* b1  = (const float*)d_in[4];
  const float* W2  = (const float*)d_in[5];
  const float* b2  = (const float*)d_in[6];
  const float* Ws1 = (const float*)d_in[7];
  const float* bs1 = (const float*)d_in[8];
  const float* Ws2 = (const float*)d_in[9];
  const float* bs2 = (const float*)d_in[10];
  float* out = (float*)d_out;

  char* wsb = (char*)d_ws;
  short* xb   = (short*)wsb;                       // 32 MiB
  float* rw   = (float*)(wsb + 33554432);          // 1 MiB region
  float* auxs = (float*)(wsb + 33816576);
  const size_t need_fixed = 33816832ull;

  // chunk width over the 9216 concat-hidden axis; multiple of 256
  const int jcands[8] = {9216, 4608, 3072, 2304, 1536, 768, 512, 256};
  int jc = 256;
  for (int ci = 0; ci < 8; ++ci) {
    if (need_fixed + (size_t)jcands[ci] * 24576ull <= ws_size) { jc = jcands[ci]; break; }
  }
  const int nc = JTOT / jc;
  short* w1t  = (short*)(wsb + need_fixed);
  short* w2t  = w1t + (size_t)jc * DIM;
  short* hbuf = w2t + (size_t)DIM * jc;

  // enable 128 KiB dynamic LDS for the 8-phase GEMM; fall back if refused
  bool big = true;
  {
    auto* f0 = gemm8p<0>; auto* f1 = gemm8p<1>; auto* f2 = gemm8p<2>;
    if (hipFuncSetAttribute(reinterpret_cast<const void*>(f0),
                            hipFuncAttributeMaxDynamicSharedMemorySize, 131072) != hipSuccess) big = false;
    if (hipFuncSetAttribute(reinterpret_cast<const void*>(f1),
                            hipFuncAttributeMaxDynamicSharedMemorySize, 131072) != hipSuccess) big = false;
    if (hipFuncSetAttribute(reinterpret_cast<const void*>(f2),
                            hipFuncAttributeMaxDynamicSharedMemorySize, 131072) != hipSuccess) big = false;
  }

  zero_aux_k<<<1, 64, 0, stream>>>(auxs);
  conv_x_k<<<(NTOK * DIM / 8) / 256, 256, 0, stream>>>(x, xb);
  router_k<<<NTOK / 4, 256, 0, stream>>>(x, Wr, br, rw, auxs);
  fin_aux_k<<<1, 64, 0, stream>>>(auxs, out + (size_t)NTOK * DIM);

  for (int c = 0; c < nc; ++c) {
    const int jbase = c * jc;
    conv_w1_k<<<dim3(jc / 64, DIM / 64), 256, 0, stream>>>(W1, Ws1, w1t, jbase, jc);
    conv_w2_k<<<dim3(jc / 64, DIM / 64), 256, 0, stream>>>(W2, Ws2, w2t, jbase, jc);
    if (big) {
      const int nx1 = jc / 256, ny = NTOK / 256;
      gemm8p<0><<<nx1 * ny, 512, 131072, stream>>>(
          xb, w1t, DIM, rw, b1, bs1, hbuf, jbase, jc, nullptr, nx1);
      const int nx2 = DIM / 256;
      if (c == 0) {
        gemm8p<1><<<nx2 * ny, 512, 131072, stream>>>(
            hbuf, w2t, jc, rw, b2, bs2, nullptr, 0, jc, out, nx2);
      } else {
        gemm8p<2><<<nx2 * ny, 512, 131072, stream>>>(
            hbuf, w2t, jc, rw, nullptr, nullptr, nullptr, 0, jc, out, nx2);
      }
    } else {
      gemm128<0><<<dim3(jc / 128, NTOK / 128), 256, 0, stream>>>(
          xb, w1t, DIM, rw, b1, bs1, hbuf, jbase, jc, nullptr);
      if (c == 0) {
        gemm128<1><<<dim3(DIM / 128, NTOK / 128), 256, 0, stream>>>(
            hbuf, w2t, jc, rw, b2, bs2, nullptr, 0, jc, out);
      } else {
        gemm128<2><<<dim3(DIM / 128, NTOK / 128), 256, 0, stream>>>(
            hbuf, w2t, jc, rw, nullptr, nullptr, nullptr, 0, jc, out);
      }
    }
  }
}

// Round 16
// 797.060 us; speedup vs baseline: 1.8974x; 1.8974x over previous
//
#include <hip/hip_runtime.h>
#include <hip/hip_bf16.h>
#include <stdint.h>

#define DEV static __device__ __forceinline__

typedef __attribute__((ext_vector_type(4))) float f32x4;
typedef __attribute__((ext_vector_type(8))) short bf16x8;
typedef __attribute__((ext_vector_type(4))) float float4v;

constexpr int NBATCH = 4;
constexpr int SEQ    = 2048;
constexpr int DIM    = 2048;      // D
constexpr int NEXP   = 8;
constexpr int HEXP   = 1024;
constexpr int DSH    = 1024;
constexpr int NTOK   = NBATCH * SEQ;       // 8192
constexpr int JEXP   = NEXP * HEXP;        // 8192
constexpr int JTOT   = JEXP + DSH;         // 9216

DEV short f2bf(float f) {
  __hip_bfloat16 b = __float2bfloat16(f);
  union { __hip_bfloat16 b; short s; } u; u.b = b; return u.s;
}

// async global->LDS, 16B per lane; LDS dest is wave-uniform base + lane*16
DEV void gload16(const void* gp, const void* lp) {
  __builtin_amdgcn_global_load_lds(
      (__attribute__((address_space(1))) void*)(uintptr_t)gp,
      (__attribute__((address_space(3))) void*)(uint32_t)(uintptr_t)lp,
      16, 0, 0);
}

// ---------------- x -> bf16 ----------------
__global__ void conv_x_k(const float* __restrict__ x, short* __restrict__ xb) {
  size_t i = (size_t)blockIdx.x * blockDim.x + threadIdx.x;
  const float4v* s = reinterpret_cast<const float4v*>(x) + i * 2;
  float4v a = s[0], b = s[1];
  bf16x8 o;
  o[0] = f2bf(a.x); o[1] = f2bf(a.y); o[2] = f2bf(a.z); o[3] = f2bf(a.w);
  o[4] = f2bf(b.x); o[5] = f2bf(b.y); o[6] = f2bf(b.z); o[7] = f2bf(b.w);
  *reinterpret_cast<bf16x8*>(xb + i * 8) = o;
}

// ---------------- router: logits, softmax, aux partial sums ----------------
__global__ __launch_bounds__(256) void router_k(
    const float* __restrict__ x, const float* __restrict__ Wr,
    const float* __restrict__ br, float* __restrict__ rw,
    float* __restrict__ auxs) {
  const int wave = threadIdx.x >> 6, lane = threadIdx.x & 63;
  const int t = blockIdx.x * 4 + wave;
  const float* xr = x + (size_t)t * DIM;
  float a[NEXP];
#pragma unroll
  for (int e = 0; e < NEXP; ++e) a[e] = 0.f;
  for (int i = 0; i < DIM / 64; ++i) {
    int k = i * 64 + lane;
    float xv = xr[k];
    const float* w = Wr + (size_t)k * NEXP;
#pragma unroll
    for (int e = 0; e < NEXP; ++e) a[e] = fmaf(xv, w[e], a[e]);
  }
#pragma unroll
  for (int e = 0; e < NEXP; ++e) {
    float v = a[e];
#pragma unroll
    for (int off = 32; off > 0; off >>= 1) v += __shfl_xor(v, off, 64);
    a[e] = v + br[e];
  }
  float mx = a[0];
#pragma unroll
  for (int e = 1; e < NEXP; ++e) mx = fmaxf(mx, a[e]);
  float s = 0.f;
#pragma unroll
  for (int e = 0; e < NEXP; ++e) { a[e] = expf(a[e] - mx); s += a[e]; }
  float inv = 1.f / s;
#pragma unroll
  for (int e = 0; e < NEXP; ++e) a[e] *= inv;
  if (lane == 0) {
#pragma unroll
    for (int e = 0; e < NEXP; ++e) rw[(size_t)t * NEXP + e] = a[e];
  }
  __shared__ float blk[NEXP];
  if (threadIdx.x < NEXP) blk[threadIdx.x] = 0.f;
  __syncthreads();
  if (lane == 0) {
#pragma unroll
    for (int e = 0; e < NEXP; ++e) atomicAdd(&blk[e], a[e]);
  }
  __syncthreads();
  if (threadIdx.x < NEXP) atomicAdd(&auxs[threadIdx.x], blk[threadIdx.x]);
}

__global__ void zero_aux_k(float* auxs) {
  if (threadIdx.x < NEXP) auxs[threadIdx.x] = 0.f;
}

__global__ void fin_aux_k(const float* __restrict__ auxs, float* __restrict__ dst) {
  if (threadIdx.x == 0) {
    float s = 0.f;
    for (int e = 0; e < NEXP; ++e) {
      float u = auxs[e] / (float)NTOK - (1.0f / NEXP);
      s += u * u;
    }
    dst[0] = (s / NEXP) * 0.01f;
  }
}

// ---------- W1cat^T chunk: dst[jloc][k] (ld=DIM), j = jbase+jloc ----------
__global__ __launch_bounds__(256) void conv_w1_k(
    const float* __restrict__ W1, const float* __restrict__ Ws1,
    short* __restrict__ dst, int jbase, int jc) {
  __shared__ float tile[64][65];
  const int j0 = jbase + blockIdx.x * 64;
  const int k0 = blockIdx.y * 64;
  const int tx = threadIdx.x & 63;
  const int ty = threadIdx.x >> 6;
#pragma unroll
  for (int i = 0; i < 16; ++i) {
    int kk = ty * 16 + i;
    int j = j0 + tx, k = k0 + kk;
    float v;
    if (j < JEXP) {
      int e = j >> 10, h = j & 1023;
      v = W1[(size_t)e * DIM * HEXP + (size_t)k * HEXP + h];
    } else {
      v = Ws1[(size_t)k * DSH + (j - JEXP)];
    }
    tile[kk][tx] = v;
  }
  __syncthreads();
#pragma unroll
  for (int i = 0; i < 16; ++i) {
    int jj = ty * 16 + i;
    int jloc = j0 - jbase + jj;
    dst[(size_t)jloc * DIM + k0 + tx] = f2bf(tile[tx][jj]);
  }
}

// ---------- W2cat^T chunk: dst[d][jloc] (ld=jc); shared rows pre-scaled 0.1 ----------
__global__ __launch_bounds__(256) void conv_w2_k(
    const float* __restrict__ W2, const float* __restrict__ Ws2,
    short* __restrict__ dst, int jbase, int jc) {
  __shared__ float tile[64][65];
  const int j0 = jbase + blockIdx.x * 64;
  const int d0 = blockIdx.y * 64;
  const int tx = threadIdx.x & 63;
  const int ty = threadIdx.x >> 6;
#pragma unroll
  for (int i = 0; i < 16; ++i) {
    int jj = ty * 16 + i;
    int j = j0 + jj;
    float v;
    if (j < JEXP) {
      int e = j >> 10, h = j & 1023;
      v = W2[(size_t)e * HEXP * DIM + (size_t)h * DIM + d0 + tx];
    } else {
      v = 0.1f * Ws2[(size_t)(j - JEXP) * DIM + d0 + tx];
    }
    tile[jj][tx] = v;
  }
  __syncthreads();
#pragma unroll
  for (int i = 0; i < 16; ++i) {
    int dd = ty * 16 + i;
    dst[(size_t)(d0 + dd) * jc + (j0 - jbase) + tx] = f2bf(tile[tx][dd]);
  }
}

// ===== 256x128 GEMM, 8 waves (4M x 2N), wave tile 64x64, BK=32 (round-9 base),
// THREE 24-KB LDS slots (72 KB) -> 2 blocks/CU; launch_bounds(512,4) -> 128 VGPR
// cap (measured ~116 incl. AGPR acc -> no spill).
// Ring-3 + counted vmcnt(3) (round-11, best measured: 798 us total).
// Ledger (3 gloads per STG: A 2 + B 1): prologue STG(0), STG(1) [6 outstanding];
// tile t waits vmcnt(3) -> drains STG(t), leaves STG(t+1) in flight across the
// whole tile; barrier; STG(t+2) into slot (t+2)%3 == (t-1)%3 (safe: its
// readers' ds_reads precede their tile-(t-1) MFMAs which precede this barrier).
// Tail: vmcnt(0) at t=NT-1 only.
// LDS swizzle (round-4, conflict-free): LDS[row][p] holds chunk p ^ ((row>>1)&3).
template <int MODE>
__global__ __launch_bounds__(512, 4) void gemmA(
    const short* __restrict__ A, const short* __restrict__ Bt, int K,
    const float* __restrict__ rw,
    const float* __restrict__ bias_a, const float* __restrict__ bias_b,
    short* __restrict__ hOut, int jbase, int jc,
    float* __restrict__ out, int nx) {
  extern __shared__ short smem[];       // 3 slots x 12288 shorts (A 8192 + B 4096)
  const int tid = threadIdx.x;
  const int w = tid >> 6, lane = tid & 63;
  const int wm = w >> 1, wn = w & 1;

  // bijective XCD swizzle of linear block id
  const int nwg = nx * (NTOK / 256);
  int orig = blockIdx.x;
  const int q = nwg >> 3, r = nwg & 7;
  const int xcd = orig & 7, off = orig >> 3;
  const int bid = (xcd < r ? xcd * (q + 1) : r * (q + 1) + (xcd - r) * q) + off;
  const int bx = bid % nx, by = bid / nx;
  const int m0 = by * 256, n0 = bx * 128;

  f32x4 acc[4][4] = {};

  // LDS read offset within a slot: row*64B + (kchunk ^ ((row>>1)&3))*16B,
  // row = base + (lane&15)
  const int aoff = ((lane & 15) << 6) + ((((lane >> 4) ^ ((lane >> 1) & 3)) & 3) << 4);

  // staging: A rows w*32 + {0,16} + (lane>>2)  (2 issues);
  //          B rows w*16 + (lane>>2)           (1 issue).
  // dest chunk lane&3, src chunk = (lane&3) ^ ((lane>>3)&3)
  // [= destchunk ^ ((row>>1)&3); row bits [2:1] == (lane>>3)&3 for all issues]
  const int srow = lane >> 2;
  const int scol = (((lane & 3) ^ ((lane >> 3) & 3)) << 3);
  const short* gA0 = A + (size_t)(m0 + w * 32 + srow) * K + scol;
  const short* gB0 = Bt + (size_t)(n0 + w * 16 + srow) * K + scol;
  const size_t k16 = (size_t)16 * K;
  const int NT = K >> 5;

  // slot s at smem + s*12288 (shorts): A rows at +w*1024, B at +8192 + w*512
#define STG(GOFF, SOFF) {                                                          \
    short* lA_ = smem + (SOFF) + w * 1024;                                         \
    short* lB_ = smem + (SOFF) + 8192 + w * 512;                                   \
    gload16(gA0 + (GOFF), lA_);                                                    \
    gload16(gA0 + k16 + (GOFF), lA_ + 512);                                        \
    gload16(gB0 + (GOFF), lB_); }

  // prologue: stage tiles 0 (slot0) and 1 (slot1)
  STG(0, 0);
  if (NT > 1) STG(32, 12288);

  int curOff = 0;        // compute slot offset (shorts): (t%3)*12288
  int stgOff = 24576;    // stage slot offset: ((t+2)%3)*12288
  size_t gOff = 64;      // global column offset (shorts) for tile t+2

  for (int t = 0; t < NT; ++t) {
    if (t < NT - 1) { asm volatile("s_waitcnt vmcnt(3)" ::: "memory"); }
    else            { asm volatile("s_waitcnt vmcnt(0)" ::: "memory"); }
    __builtin_amdgcn_s_barrier();
    asm volatile("" ::: "memory");
    if (t + 2 < NT) STG(gOff, stgOff);
    const char* base = (const char*)(smem + curOff);
    const char* pa = base + wm * 4096 + aoff;           // wm*64 rows * 64B
    const char* pb = base + 16384 + wn * 4096 + aoff;   // B region + wn*64 rows
    bf16x8 bf[4], af[4];
#pragma unroll
    for (int n = 0; n < 4; ++n) bf[n] = *(const bf16x8*)(pb + n * 1024);
#pragma unroll
    for (int m = 0; m < 4; ++m) af[m] = *(const bf16x8*)(pa + m * 1024);
#pragma unroll
    for (int m = 0; m < 4; ++m)
#pragma unroll
      for (int n = 0; n < 4; ++n)
        acc[m][n] = __builtin_amdgcn_mfma_f32_16x16x32_bf16(af[m], bf[n], acc[m][n], 0, 0, 0);
    // rotate ring: stg(t+1) = cur(t); cur(t+1) = cur(t)+1 mod 3
    int nxt = curOff;
    curOff = (curOff == 24576) ? 0 : curOff + 12288;
    stgOff = nxt;
    gOff += 32;
  }
#undef STG

  // ---------------- epilogue ----------------
  const int r0 = (lane >> 4) * 4;
  const int ccol = lane & 15;
#pragma unroll
  for (int m = 0; m < 4; ++m) {
#pragma unroll
    for (int i = 0; i < 4; ++i) {
      const int trow = m0 + wm * 64 + m * 16 + r0 + i;
      if (MODE == 0) {
#pragma unroll
        for (int n = 0; n < 4; ++n) {
          const int col = n0 + wn * 64 + n * 16 + ccol;
          const int j = jbase + col;
          float v = acc[m][n][i];
          float bias = (j < JEXP) ? bias_a[j] : bias_b[j - JEXP];
          float val = v + bias;
          float g = 0.5f * val * (1.0f + erff(val * 0.70710678118654752f));
          float wgt = (j < JEXP) ? rw[(size_t)trow * NEXP + (j >> 10)] : 1.0f;
          hOut[(size_t)trow * jc + col] = f2bf(g * wgt);
        }
      } else if (MODE == 1) {
        float rw8[8];
#pragma unroll
        for (int e = 0; e < 8; ++e) rw8[e] = rw[(size_t)trow * NEXP + e];
#pragma unroll
        for (int n = 0; n < 4; ++n) {
          const int col = n0 + wn * 64 + n * 16 + ccol;
          float bias = 0.1f * bias_b[col];
#pragma unroll
          for (int e = 0; e < 8; ++e) bias += rw8[e] * bias_a[(size_t)e * DIM + col];
          out[(size_t)trow * DIM + col] = acc[m][n][i] + bias;
        }
      } else {
#pragma unroll
        for (int n = 0; n < 4; ++n) {
          const int col = n0 + wn * 64 + n * 16 + ccol;
          out[(size_t)trow * DIM + col] += acc[m][n][i];
        }
      }
    }
  }
}

// ================= fallback 128x128 GEMM (round-1, proven) =================
template <int MODE>
__global__ __launch_bounds__(256) void gemm128(
    const short* __restrict__ A, const short* __restrict__ Bt, int K,
    const float* __restrict__ rw,
    const float* __restrict__ bias_a, const float* __restrict__ bias_b,
    short* __restrict__ hOut, int jbase, int jc,
    float* __restrict__ out) {
  __shared__ short As[128 * 64];
  __shared__ short Bs[128 * 64];
  const int tid = threadIdx.x;
  const int wave = tid >> 6, lane = tid & 63;
  const int wr = wave >> 1, wc = wave & 1;
  const int m0 = blockIdx.y * 128;
  const int n0 = blockIdx.x * 128;

  f32x4 acc[4][4] = {};

  const int srow = wave * 8 + (lane >> 3);
  const int scol = (((lane & 7) ^ (lane >> 3)) << 3);
  const short* gA = A + (size_t)(m0 + srow) * K + scol;
  const short* gB = Bt + (size_t)(n0 + srow) * K + scol;
  const short* lA = As + wave * 512;
  const short* lB = Bs + wave * 512;

  const int rrow = lane & 15;
  const int koff = lane >> 4;
  const int kxor = lane & 7;

  for (int kt = 0; kt < K; kt += 64) {
#pragma unroll
    for (int i = 0; i < 4; ++i) {
      gload16(gA + (size_t)i * 32 * K + kt, lA + i * 2048);
      gload16(gB + (size_t)i * 32 * K + kt, lB + i * 2048);
    }
    asm volatile("s_waitcnt vmcnt(0)" ::: "memory");
    __syncthreads();
#pragma unroll
    for (int kk = 0; kk < 2; ++kk) {
      bf16x8 af[4], bfv[4];
#pragma unroll
      for (int m = 0; m < 4; ++m) {
        int row = wr * 64 + m * 16 + rrow;
        int chunk = (kk * 4 + koff) ^ kxor;
        af[m] = *reinterpret_cast<const bf16x8*>(&As[row * 64 + chunk * 8]);
      }
#pragma unroll
      for (int n = 0; n < 4; ++n) {
        int row = wc * 64 + n * 16 + rrow;
        int chunk = (kk * 4 + koff) ^ kxor;
        bfv[n] = *reinterpret_cast<const bf16x8*>(&Bs[row * 64 + chunk * 8]);
      }
#pragma unroll
      for (int m = 0; m < 4; ++m)
#pragma unroll
        for (int n = 0; n < 4; ++n)
          acc[m][n] = __builtin_amdgcn_mfma_f32_16x16x32_bf16(af[m], bfv[n], acc[m][n], 0, 0, 0);
    }
    __syncthreads();
  }

  const int r0 = (lane >> 4) * 4;
  const int ccol = lane & 15;
#pragma unroll
  for (int m = 0; m < 4; ++m) {
#pragma unroll
    for (int n = 0; n < 4; ++n) {
      int col = n0 + wc * 64 + n * 16 + ccol;
#pragma unroll
      for (int i = 0; i < 4; ++i) {
        int t = m0 + wr * 64 + m * 16 + r0 + i;
        float v = acc[m][n][i];
        if (MODE == 0) {
          int j = jbase + col;
          float bias = (j < JEXP) ? bias_a[j] : bias_b[j - JEXP];
          float val = v + bias;
          float g = 0.5f * val * (1.0f + erff(val * 0.70710678118654752f));
          float wg = (j < JEXP) ? rw[(size_t)t * NEXP + (j >> 10)] : 1.0f;
          hOut[(size_t)t * jc + col] = f2bf(g * wg);
        } else if (MODE == 1) {
          float bias = 0.1f * bias_b[col];
#pragma unroll
          for (int e = 0; e < NEXP; ++e)
            bias += rw[(size_t)t * NEXP + e] * bias_a[(size_t)e * DIM + col];
          out[(size_t)t * DIM + col] = v + bias;
        } else {
          out[(size_t)t * DIM + col] += v;
        }
      }
    }
  }
}

extern "C" void kernel_launch(void* const* d_in, const int* in_sizes, int n_in,
                              void* d_out, int out_size, void* d_ws, size_t ws_size,
                              hipStream_t stream) {
  const float* x   = (const float*)d_in[0];
  const float* Wr  = (const float*)d_in[1];
  const float* br  = (const float*)d_in[2];
  const float* W1  = (const float*)d_in[3];
  const float* b1  = (const float*)d_in[4];
  const float* W2  = (const float*)d_in[5];
  const float* b2  = (const float*)d_in[6];
  const float* Ws1 = (const float*)d_in[7];
  const float* bs1 = (const float*)d_in[8];
  const float* Ws2 = (const float*)d_in[9];
  const float* bs2 = (const float*)d_in[10];
  float* out = (float*)d_out;

  char* wsb = (char*)d_ws;
  short* xb   = (short*)wsb;                       // 32 MiB
  float* rw   = (float*)(wsb + 33554432);          // 1 MiB region
  float* auxs = (float*)(wsb + 33816576);
  const size_t need_fixed = 33816832ull;

  // chunk width over the 9216 concat-hidden axis; multiple of 256
  const int jcands[8] = {9216, 4608, 3072, 2304, 1536, 768, 512, 256};
  int jc = 256;
  for (int ci = 0; ci < 8; ++ci) {
    if (need_fixed + (size_t)jcands[ci] * 24576ull <= ws_size) { jc = jcands[ci]; break; }
  }
  const int nc = JTOT / jc;
  short* w1t  = (short*)(wsb + need_fixed);
  short* w2t  = w1t + (size_t)jc * DIM;
  short* hbuf = w2t + (size_t)DIM * jc;

  // enable 72 KiB dynamic LDS for the big-tile GEMM; fall back if refused
  bool big = true;
  {
    auto* f0 = gemmA<0>; auto* f1 = gemmA<1>; auto* f2 = gemmA<2>;
    if (hipFuncSetAttribute(reinterpret_cast<const void*>(f0),
                            hipFuncAttributeMaxDynamicSharedMemorySize, 73728) != hipSuccess) big = false;
    if (hipFuncSetAttribute(reinterpret_cast<const void*>(f1),
                            hipFuncAttributeMaxDynamicSharedMemorySize, 73728) != hipSuccess) big = false;
    if (hipFuncSetAttribute(reinterpret_cast<const void*>(f2),
                            hipFuncAttributeMaxDynamicSharedMemorySize, 73728) != hipSuccess) big = false;
  }

  zero_aux_k<<<1, 64, 0, stream>>>(auxs);
  conv_x_k<<<(NTOK * DIM / 8) / 256, 256, 0, stream>>>(x, xb);
  router_k<<<NTOK / 4, 256, 0, stream>>>(x, Wr, br, rw, auxs);
  fin_aux_k<<<1, 64, 0, stream>>>(auxs, out + (size_t)NTOK * DIM);

  for (int c = 0; c < nc; ++c) {
    const int jbase = c * jc;
    conv_w1_k<<<dim3(jc / 64, DIM / 64), 256, 0, stream>>>(W1, Ws1, w1t, jbase, jc);
    conv_w2_k<<<dim3(jc / 64, DIM / 64), 256, 0, stream>>>(W2, Ws2, w2t, jbase, jc);
    if (big) {
      const int nx1 = jc / 128, ny = NTOK / 256;
      gemmA<0><<<nx1 * ny, 512, 73728, stream>>>(
          xb, w1t, DIM, rw, b1, bs1, hbuf, jbase, jc, nullptr, nx1);
      const int nx2 = DIM / 128;
      if (c == 0) {
        gemmA<1><<<nx2 * ny, 512, 73728, stream>>>(
            hbuf, w2t, jc, rw, b2, bs2, nullptr, 0, jc, out, nx2);
      } else {
        gemmA<2><<<nx2 * ny, 512, 73728, stream>>>(
            hbuf, w2t, jc, rw, nullptr, nullptr, nullptr, 0, jc, out, nx2);
      }
    } else {
      gemm128<0><<<dim3(jc / 128, NTOK / 128), 256, 0, stream>>>(
          xb, w1t, DIM, rw, b1, bs1, hbuf, jbase, jc, nullptr);
      if (c == 0) {
        gemm128<1><<<dim3(DIM / 128, NTOK / 128), 256, 0, stream>>>(
            hbuf, w2t, jc, rw, b2, bs2, nullptr, 0, jc, out);
      } else {
        gemm128<2><<<dim3(DIM / 128, NTOK / 128), 256, 0, stream>>>(
            hbuf, w2t, jc, rw, nullptr, nullptr, nullptr, 0, jc, out);
      }
    }
  }
}